// Round 8
// baseline (784.466 us; speedup 1.0000x reference)
//
#include <hip/hip_runtime.h>
#include <cstdint>
#include <cstddef>

#define Nn   50000
#define Ee   800000
#define ETOT 850000   // edges + self loops
#define HID  128
#define Gg   16
#define RSZ  6250     // Nn/8 : dst-range size per XCD team
#define DMAX 64       // padded adjacency slots per node (max degree ~45 here)
#define NEG_SLOPE 0.2f
#define EPS_GN 1e-5f

typedef __attribute__((ext_vector_type(8))) short short8;
typedef __attribute__((ext_vector_type(4))) float f32x4;

static __device__ __forceinline__ float lrelu(float v) { return v > 0.f ? v : NEG_SLOPE * v; }

// round-to-nearest-even fp32 -> bf16 (low 16 bits of uint)
static __device__ __forceinline__ unsigned int f2bf(float x) {
    unsigned int u = __float_as_uint(x);
    return (u + 0x7fffu + ((u >> 16) & 1u)) >> 16;
}
static __device__ __forceinline__ float bf_lo(unsigned int u) { return __uint_as_float(u << 16); }
static __device__ __forceinline__ float bf_hi(unsigned int u) { return __uint_as_float(u & 0xffff0000u); }

// GraphNorm affine from raw sums: out = x*A + B reproduces
// (x - s*m)/sqrt(var+eps)*w + b with var = E[x^2] - (2s - s^2) m^2.
static __device__ __forceinline__ void gn_ab(float sx, float sq, float cn,
                                             float wv, float bv, float sv,
                                             float& A, float& B) {
    float m    = sx / cn;
    float msq  = sq / cn;
    float varo = msq - (2.f * sv - sv * sv) * m * m;
    float inv  = rsqrtf(varo + EPS_GN);
    A = inv * wv;
    B = bv - sv * m * A;
}

// ---------------------------------------------------------------------------
// Weight prep: bf16 transpose of in_W and Wg ([n][k] layout) + per-graph node
// counts (batch sorted -> run flush, 8 nodes per thread).
// ---------------------------------------------------------------------------
__global__ void prep_w(const float* __restrict__ in_W, const float* __restrict__ Wg,
                       const int* __restrict__ batch,
                       short* __restrict__ Wt0, short* __restrict__ Wtl,
                       float* __restrict__ cntf) {
    int i = blockIdx.x * 256 + threadIdx.x;
    if (i < 8192) {                       // in-proj: n = i>>6, k = i&63
        int n = i >> 6, k = i & 63;
        Wt0[i] = (short)f2bf(in_W[k * 128 + n]);
    } else if (i < 73728) {
        int j = i - 8192;                 // j = l*16384 + n*128 + k
        int l = j >> 14;
        int rkn = j & 16383;
        int n = rkn >> 7, k = rkn & 127;
        Wtl[j] = (short)f2bf(Wg[l * 16384 + k * 128 + n]);
    } else if (i < 73728 + 6250) {
        int base = (i - 73728) * 8;
        int g = batch[base];
        float c = 1.f;
        for (int k = 1; k < 8; k++) {
            int gk = batch[base + k];
            if (gk != g) { atomicAdd(&cntf[g], c); g = gk; c = 1.f; }
            else c += 1.f;
        }
        atomicAdd(&cntf[g], c);
    }
}

// ---------------------------------------------------------------------------
// Padded adjacency build, single pass, XCD-partitioned (block b&7 = dst range).
// ---------------------------------------------------------------------------
__global__ void scatter_pad(const int* __restrict__ esrc, const int* __restrict__ edst,
                            int* __restrict__ cnt, int* __restrict__ colPad) {
    int r  = blockIdx.x & 7;
    int cb = blockIdx.x >> 3;
    int nb = gridDim.x >> 3;
    int lo = r * RSZ, hi = lo + RSZ;
    for (int i = cb * 256 + threadIdx.x; i < ETOT; i += nb * 256) {
        int dst = (i < Ee) ? edst[i] : (i - Ee);
        if (dst >= lo && dst < hi) {
            int src = (i < Ee) ? esrc[i] : dst;
            int pos = atomicAdd(&cnt[dst], 1);
            if (pos < DMAX) colPad[dst * DMAX + pos] = src;
        }
    }
}

// ---------------------------------------------------------------------------
// MFMA bf16 GEMM: C[M,128] = affine?(A)[M,K] @ W[K,128] (+bias), bf16x2 out.
// Block 128x128, 4 waves (2x2 of 64x64), 16x16x32 bf16 MFMA.
// AFFINE: GraphNorm affine computed in-block from raw sums (<=2 graphs per
// 128-row tile since graphs are ~3125 nodes) into an LDS table.
// SCORES: fused es/ed (attention logits) during the C repack read-out.
// ---------------------------------------------------------------------------
template <int K, bool ABF16, bool AFFINE, bool BIAS, bool SCORES>
__global__ __launch_bounds__(256) void gemm_mfma(const float* __restrict__ Agf,
                                                 const unsigned int* __restrict__ Agb,
                                                 const int* __restrict__ batch,
                                                 const float* __restrict__ sxP,
                                                 const float* __restrict__ sqP,
                                                 const float* __restrict__ cntf,
                                                 const float* __restrict__ gw,
                                                 const float* __restrict__ gb,
                                                 const float* __restrict__ gs,
                                                 const short* __restrict__ Wt,
                                                 const float* __restrict__ bias,
                                                 const float* __restrict__ asrc,
                                                 const float* __restrict__ adst,
                                                 float* __restrict__ es,
                                                 float* __restrict__ ed,
                                                 unsigned int* __restrict__ Cb,
                                                 int M) {
    constexpr int KP = K + 8;                    // padded shorts per A row
    constexpr int ABYTES = 128 * KP * 2;
    constexpr int CBYTES = 64 * 130 * 4;
    constexpr int SBYTES = ABYTES > CBYTES ? ABYTES : CBYTES;
    __shared__ __align__(16) char smem[SBYTES];
    __shared__ float AffA[2][132], AffB[2][132];
    short* As = (short*)smem;
    float* Cs = (float*)smem;   // overlays As (used only after all MFMA reads)

    int t    = threadIdx.x;
    int lane = t & 63;
    int w    = t >> 6;
    int wm   = (w & 1) * 64;
    int wn   = (w >> 1) * 64;
    int row0 = blockIdx.x * 128;

    int g0 = 0, g1 = 0;
    if (AFFINE) {
        g0 = batch[row0];
        int lastr = row0 + 127 < M - 1 ? row0 + 127 : M - 1;
        g1 = batch[lastr];
        int sel = t >> 7;            // 0 or 1
        int c   = t & 127;
        int g   = sel ? g1 : g0;
        float A, B;
        gn_ab(sxP[g * 128 + c], sqP[g * 128 + c], cntf[g], gw[c], gb[c], gs[c], A, B);
        AffA[sel][c] = A;
        AffB[sel][c] = B;
        __syncthreads();
    }

    // ---- stage A -> bf16 LDS ----
    if (!ABF16) {
        constexpr int F4R = K / 4;               // float4 per row
        constexpr int ITERS = 128 * F4R / 256;
#pragma unroll
        for (int i = 0; i < ITERS; i++) {
            int f4 = t + 256 * i;
            int r  = f4 / F4R;
            int c4 = f4 % F4R;
            float4 v = make_float4(0.f, 0.f, 0.f, 0.f);
            int gr = row0 + r;
            if (gr < M) v = *(const float4*)(Agf + (size_t)gr * K + c4 * 4);
            uint2 pk;
            pk.x = f2bf(v.x) | (f2bf(v.y) << 16);
            pk.y = f2bf(v.z) | (f2bf(v.w) << 16);
            *(uint2*)(As + r * KP + c4 * 4) = pk;
        }
    } else {
        constexpr int U2R = K / 4;               // uint2 per row
        constexpr int ITERS = 128 * U2R / 256;
#pragma unroll
        for (int i = 0; i < ITERS; i++) {
            int u2 = t + 256 * i;
            int r  = u2 / U2R;
            int c2 = u2 % U2R;                   // uint2 index: channels c2*4..+3
            uint2 v = make_uint2(0u, 0u);
            int gr = row0 + r;
            if (gr < M) {
                v = *(const uint2*)(Agb + (size_t)gr * (K / 2) + c2 * 2);
                if (AFFINE) {
                    int sel = (batch[gr] == g0) ? 0 : 1;
                    float4 Av = *(const float4*)(&AffA[sel][c2 * 4]);
                    float4 Bv = *(const float4*)(&AffB[sel][c2 * 4]);
                    float x0 = bf_lo(v.x) * Av.x + Bv.x;
                    float x1 = bf_hi(v.x) * Av.y + Bv.y;
                    float x2 = bf_lo(v.y) * Av.z + Bv.z;
                    float x3 = bf_hi(v.y) * Av.w + Bv.w;
                    v.x = f2bf(x0) | (f2bf(x1) << 16);
                    v.y = f2bf(x2) | (f2bf(x3) << 16);
                }
            }
            *(uint2*)(As + r * KP + c2 * 4) = v;
        }
    }
    __syncthreads();

    // ---- MFMA main loop ----
    f32x4 acc[4][4] = {};
    int am = wm + (lane & 15);
    int aq = (lane >> 4) * 8;
    const short* wb = Wt + (size_t)(wn + (lane & 15)) * K + aq;
#pragma unroll
    for (int kk = 0; kk < K / 32; kk++) {
        short8 a[4], b[4];
#pragma unroll
        for (int nt = 0; nt < 4; nt++)
            b[nt] = *(const short8*)(wb + nt * 16 * K + kk * 32);
#pragma unroll
        for (int mt = 0; mt < 4; mt++)
            a[mt] = *(const short8*)(As + (am + mt * 16) * KP + kk * 32 + aq);
#pragma unroll
        for (int mt = 0; mt < 4; mt++)
#pragma unroll
            for (int nt = 0; nt < 4; nt++)
                acc[mt][nt] = __builtin_amdgcn_mfma_f32_16x16x32_bf16(
                    a[mt], b[nt], acc[mt][nt], 0, 0, 0);
    }

    // ---- epilogue: LDS repack -> packed bf16x2 (+bias, + fused scores) ----
    // C/D layout: col = lane&15 (within 16-tile), row = (lane>>4)*4 + reg
    float bv[4] = {0.f, 0.f, 0.f, 0.f};
    if (BIAS) {
#pragma unroll
        for (int nt = 0; nt < 4; nt++) bv[nt] = bias[wn + nt * 16 + (lane & 15)];
    }
    float avv[8], dvv[8];
    if (SCORES) {
        int q = t & 15;
#pragma unroll
        for (int k = 0; k < 8; k++) {
            avv[k] = asrc[q * 8 + k];
            dvv[k] = adst[q * 8 + k];
        }
    }
#pragma unroll
    for (int half = 0; half < 2; half++) {
        __syncthreads();   // As reads done / previous pack done
        if ((w & 1) == half) {
#pragma unroll
            for (int mt = 0; mt < 4; mt++)
#pragma unroll
                for (int reg = 0; reg < 4; reg++) {
                    int lr = mt * 16 + (lane >> 4) * 4 + reg;   // 0..63
#pragma unroll
                    for (int nt = 0; nt < 4; nt++)
                        Cs[lr * 130 + wn + nt * 16 + (lane & 15)] =
                            acc[mt][nt][reg] + bv[nt];
                }
        }
        __syncthreads();
#pragma unroll
        for (int i = 0; i < 4; i++) {
            int u4 = t + 256 * i;       // 0..1023
            int r  = u4 >> 4;           // 0..63
            int cu = (u4 & 15) * 4;     // uint col
            int grow = row0 + half * 64 + r;
            if (grow < M) {
                const float* cp = Cs + r * 130 + cu * 2;
                float2 p0 = *(const float2*)(cp + 0);
                float2 p1 = *(const float2*)(cp + 2);
                float2 p2 = *(const float2*)(cp + 4);
                float2 p3 = *(const float2*)(cp + 6);
                uint4 o;
                o.x = f2bf(p0.x) | (f2bf(p0.y) << 16);
                o.y = f2bf(p1.x) | (f2bf(p1.y) << 16);
                o.z = f2bf(p2.x) | (f2bf(p2.y) << 16);
                o.w = f2bf(p3.x) | (f2bf(p3.y) << 16);
                *(uint4*)(Cb + (size_t)grow * 64 + cu) = o;
                if (SCORES) {
                    float s1 = p0.x * avv[0] + p0.y * avv[1] + p1.x * avv[2] +
                               p1.y * avv[3] + p2.x * avv[4] + p2.y * avv[5] +
                               p3.x * avv[6] + p3.y * avv[7];
                    float s2 = p0.x * dvv[0] + p0.y * dvv[1] + p1.x * dvv[2] +
                               p1.y * dvv[3] + p2.x * dvv[4] + p2.y * dvv[5] +
                               p3.x * dvv[6] + p3.y * dvv[7];
                    s1 += __shfl_xor(s1, 1);
                    s2 += __shfl_xor(s2, 1);
                    if ((t & 1) == 0) {
                        int hh = (t & 15) >> 1;
                        es[(size_t)grow * 8 + hh] = s1;
                        ed[(size_t)grow * 8 + hh] = s2;
                    }
                }
            }
        }
    }
}

// ---------------------------------------------------------------------------
// GAT aggregation + fused GraphNorm stats. Block = 16 waves = 16 nodes.
// Per wave: weight phase (slot=lane>>3, head=lane&7), accumulate phase
// (half=lane>>5, sl=lane&31 holds channels 4*sl..+3, uint2 bf16x4 gather,
// 2 edges per inner step). Residual affine computed inline from prev-layer
// raw sums. Output sums/sumsq pooled in LDS (blocks are single-graph except
// ~15 boundary blocks) and flushed with one 256-atomic burst per block.
// ---------------------------------------------------------------------------
template <bool AFF>
__global__ __launch_bounds__(1024) void gat_attn(const unsigned int* __restrict__ hp,
                                                 const unsigned int* hinb,
                                                 const int* __restrict__ batch,
                                                 const float* __restrict__ sxP,
                                                 const float* __restrict__ sqP,
                                                 const float* __restrict__ cntf,
                                                 const float* __restrict__ gw,
                                                 const float* __restrict__ gb,
                                                 const float* __restrict__ gs,
                                                 const float* __restrict__ es,
                                                 const float* __restrict__ ed,
                                                 const int* __restrict__ cnt,
                                                 const int* __restrict__ colPad,
                                                 const float* __restrict__ gbias,
                                                 unsigned int* outb,
                                                 float* __restrict__ sxO,
                                                 float* __restrict__ sqO) {
    __shared__ float s_sum[128], s_sq[128];
    int t    = threadIdx.x;
    int w    = t >> 6;
    int lane = t & 63;
    int n    = blockIdx.x * 16 + w;
    int deg  = cnt[n];
    deg = deg < DMAX ? deg : DMAX;
    const int* cbp = colPad + n * DMAX;

    int slot = lane >> 3;   // edge slot (weight phase)
    int ah   = lane & 7;    // head (weight phase)
    int half = lane >> 5;   // edge parity (accumulate phase)
    int sl   = lane & 31;   // channel group: channels 4*sl .. 4*sl+3
    int hd   = sl >> 2;     // head of this lane's channels

    float edh = ed[(size_t)n * 8 + ah];
    const unsigned int* hpl = hp + sl * 2;

    float a0 = 0.f, a1 = 0.f, a2 = 0.f, a3 = 0.f;
    float dacc = 0.f;

    int e0 = 0;
    for (; e0 + 8 <= deg; e0 += 8) {
        int src_l = cbp[e0 + slot];
        float wgt = __expf(lrelu(es[(size_t)src_l * 8 + ah] + edh));
        dacc += wgt;
#pragma unroll
        for (int jj = 0; jj < 4; jj++) {
            int e = jj * 2 + half;
            int   sj = __shfl(src_l, e * 8);
            float wj = __shfl(wgt,   e * 8 + hd);
            uint2 hv = *(const uint2*)(hpl + (size_t)sj * 64);
            a0 += wj * bf_lo(hv.x);
            a1 += wj * bf_hi(hv.x);
            a2 += wj * bf_lo(hv.y);
            a3 += wj * bf_hi(hv.y);
        }
    }
    if (e0 < deg) {
        int rem = deg - e0;                       // 1..7, wave-uniform
        int ee  = e0 + slot;
        int ec  = (slot < rem) ? ee : (deg - 1);  // rows non-empty (self-loop)
        int src_l = cbp[ec];
        float wgt = (slot < rem) ? __expf(lrelu(es[(size_t)src_l * 8 + ah] + edh)) : 0.f;
        dacc += wgt;
        int steps = (rem + 1) >> 1;
        for (int jj = 0; jj < steps; jj++) {      // weights beyond rem are 0
            int e = jj * 2 + half;
            int   sj = __shfl(src_l, e * 8);
            float wj = __shfl(wgt,   e * 8 + hd);
            uint2 hv = *(const uint2*)(hpl + (size_t)sj * 64);
            a0 += wj * bf_lo(hv.x);
            a1 += wj * bf_hi(hv.x);
            a2 += wj * bf_lo(hv.y);
            a3 += wj * bf_hi(hv.y);
        }
    }

    // combine the two halves (each saw edges of one parity)
    a0 += __shfl_xor(a0, 32);
    a1 += __shfl_xor(a1, 32);
    a2 += __shfl_xor(a2, 32);
    a3 += __shfl_xor(a3, 32);

    // denominator: sum over the 8 slots sharing head `ah`
    dacc += __shfl_xor(dacc, 8);
    dacc += __shfl_xor(dacc, 16);
    dacc += __shfl_xor(dacc, 32);
    float inv  = 1.0f / (dacc + 1e-16f);
    float winv = __shfl(inv, hd);       // lane hd has ah == hd

    float o0 = 0.f, o1 = 0.f, o2 = 0.f, o3 = 0.f;
    if (half == 0) {
        size_t uo = (size_t)n * 64 + sl * 2;
        uint2 xv = *(const uint2*)(hinb + uo);
        float r0 = bf_lo(xv.x), r1 = bf_hi(xv.x), r2 = bf_lo(xv.y), r3 = bf_hi(xv.y);
        if (AFF) {
            int g = batch[n];
            float cn = cntf[g];
            int c = sl * 4;
            float A, B;
            gn_ab(sxP[g * 128 + c],     sqP[g * 128 + c],     cn, gw[c],     gb[c],     gs[c],     A, B);
            r0 = r0 * A + B;
            gn_ab(sxP[g * 128 + c + 1], sqP[g * 128 + c + 1], cn, gw[c + 1], gb[c + 1], gs[c + 1], A, B);
            r1 = r1 * A + B;
            gn_ab(sxP[g * 128 + c + 2], sqP[g * 128 + c + 2], cn, gw[c + 2], gb[c + 2], gs[c + 2], A, B);
            r2 = r2 * A + B;
            gn_ab(sxP[g * 128 + c + 3], sqP[g * 128 + c + 3], cn, gw[c + 3], gb[c + 3], gs[c + 3], A, B);
            r3 = r3 * A + B;
        }
        float4 bv = *(const float4*)(gbias + sl * 4);
        o0 = a0 * winv + bv.x + r0;
        o1 = a1 * winv + bv.y + r1;
        o2 = a2 * winv + bv.z + r2;
        o3 = a3 * winv + bv.w + r3;
        uint2 o;
        o.x = f2bf(o0) | (f2bf(o1) << 16);
        o.y = f2bf(o2) | (f2bf(o3) << 16);
        *(uint2*)(outb + uo) = o;
    }

    // ---- fused GraphNorm stats ----
    int g0b = batch[blockIdx.x * 16];
    int g1b = batch[blockIdx.x * 16 + 15];
    if (g0b == g1b) {                 // block-uniform graph (the common case)
        if (t < 128) { s_sum[t] = 0.f; s_sq[t] = 0.f; }
        __syncthreads();
        if (half == 0) {
            int c = sl * 4;
            atomicAdd(&s_sum[c],     o0); atomicAdd(&s_sq[c],     o0 * o0);
            atomicAdd(&s_sum[c + 1], o1); atomicAdd(&s_sq[c + 1], o1 * o1);
            atomicAdd(&s_sum[c + 2], o2); atomicAdd(&s_sq[c + 2], o2 * o2);
            atomicAdd(&s_sum[c + 3], o3); atomicAdd(&s_sq[c + 3], o3 * o3);
        }
        __syncthreads();
        if (t < 128)       atomicAdd(&sxO[g0b * 128 + t], s_sum[t]);
        else if (t < 256)  atomicAdd(&sqO[g0b * 128 + (t - 128)], s_sq[t - 128]);
    } else {                          // boundary block (~15 of 3125): direct
        if (half == 0) {
            int g = batch[n];
            int c = sl * 4;
            atomicAdd(&sxO[g * 128 + c],     o0); atomicAdd(&sqO[g * 128 + c],     o0 * o0);
            atomicAdd(&sxO[g * 128 + c + 1], o1); atomicAdd(&sqO[g * 128 + c + 1], o1 * o1);
            atomicAdd(&sxO[g * 128 + c + 2], o2); atomicAdd(&sqO[g * 128 + c + 2], o2 * o2);
            atomicAdd(&sxO[g * 128 + c + 3], o3); atomicAdd(&sqO[g * 128 + c + 3], o3 * o3);
        }
    }
}

// ---------------------------------------------------------------------------
// Final normalize -> d_out (fp32), affine computed inline from layer-3 sums.
// ---------------------------------------------------------------------------
__global__ __launch_bounds__(256) void gn_apply(const unsigned int* __restrict__ xb,
                                                const int* __restrict__ batch,
                                                const float* __restrict__ sx,
                                                const float* __restrict__ sq,
                                                const float* __restrict__ cntf,
                                                const float* __restrict__ gw,
                                                const float* __restrict__ gb,
                                                const float* __restrict__ gs,
                                                float* __restrict__ out) {
    int idx = blockIdx.x * 256 + threadIdx.x;
    int n = idx >> 5;
    if (n >= Nn) return;
    int c4 = (idx & 31) << 2;
    int g = batch[n];
    float cn = cntf[g];
    uint2 xv = *(const uint2*)(xb + (size_t)n * 64 + (c4 >> 1));
    float vv[4] = {bf_lo(xv.x), bf_hi(xv.x), bf_lo(xv.y), bf_hi(xv.y)};
    float4 o;
    float* op = (float*)&o;
#pragma unroll
    for (int k = 0; k < 4; k++) {
        int c = c4 + k;
        float A, B;
        gn_ab(sx[g * 128 + c], sq[g * 128 + c], cn, gw[c], gb[c], gs[c], A, B);
        op[k] = vv[k] * A + B;
    }
    *(float4*)(out + (size_t)n * 128 + c4) = o;
}

// ---------------------------------------------------------------------------
// Launch
// ---------------------------------------------------------------------------
extern "C" void kernel_launch(void* const* d_in, const int* in_sizes, int n_in,
                              void* d_out, int out_size, void* d_ws, size_t ws_size,
                              hipStream_t stream) {
    const float* x      = (const float*)d_in[0];
    const int*   eidx   = (const int*)d_in[1];
    const int*   batch  = (const int*)d_in[2];
    const float* in_W   = (const float*)d_in[3];
    const float* in_b   = (const float*)d_in[4];
    const float* Wg     = (const float*)d_in[5];
    const float* attS   = (const float*)d_in[6];
    const float* attD   = (const float*)d_in[7];
    const float* gat_b  = (const float*)d_in[8];
    const float* gn_w   = (const float*)d_in[9];
    const float* gn_b   = (const float*)d_in[10];
    const float* gn_s   = (const float*)d_in[11];

    const int* esrc = eidx;
    const int* edst = eidx + Ee;

    char* p = (char*)d_ws;
    auto carve = [&](size_t bytes) {
        void* r = (void*)p;
        p += (bytes + 255) & ~(size_t)255;
        return r;
    };
    unsigned int* h0b = (unsigned int*)carve((size_t)Nn * 64 * 4);  // bf16x2 hidden
    unsigned int* hp  = (unsigned int*)carve((size_t)Nn * 64 * 4);  // bf16x2 h'
    unsigned int* h2b = (unsigned int*)carve((size_t)Nn * 64 * 4);  // bf16x2 state
    float* es   = (float*)carve((size_t)Nn * 8 * 4);
    float* ed   = (float*)carve((size_t)Nn * 8 * 4);
    // single zeroed region: adjacency counts | per-graph node counts | 4x stats
    const size_t ZN = (size_t)Nn + 16 + 4 * 4096;
    int*   cnt  = (int*)carve(ZN * 4);
    float* cntf = (float*)(cnt + Nn);
    float* stats = cntf + 16;                 // layer l: sumx = stats + l*4096, sumxx = +2048
    int* colPad = (int*)carve((size_t)Nn * DMAX * 4);
    short* Wt0  = (short*)carve((size_t)128 * 64 * 2);
    short* Wtl  = (short*)carve((size_t)4 * 128 * 128 * 2);

    // ---- zero + prep + adjacency build ----
    hipMemsetAsync(cnt, 0, ZN * 4, stream);
    prep_w<<<313, 256, 0, stream>>>(in_W, Wg, batch, Wt0, Wtl, cntf);
    scatter_pad<<<3072, 256, 0, stream>>>(esrc, edst, cnt, colPad);

    const int gemm_grid = (Nn + 127) / 128;  // 391

    // ---- input projection: x fp32 -> h0b bf16 (+bias) ----
    gemm_mfma<64, false, false, true, false><<<gemm_grid, 256, 0, stream>>>(
        x, nullptr, nullptr, nullptr, nullptr, nullptr, nullptr, nullptr, nullptr,
        Wt0, in_b, nullptr, nullptr, nullptr, nullptr, h0b, Nn);

    // ---- layers ----
    for (int l = 0; l < 4; l++) {
        const short* Wl = Wtl + (size_t)l * 128 * 128;
        float* sxO = stats + (size_t)l * 4096;
        float* sqO = sxO + 2048;
        if (l == 0) {
            gemm_mfma<128, true, false, false, true><<<gemm_grid, 256, 0, stream>>>(
                nullptr, h0b, nullptr, nullptr, nullptr, nullptr, nullptr, nullptr, nullptr,
                Wl, nullptr, attS, attD, es, ed, hp, Nn);
            gat_attn<false><<<Nn / 16, 1024, 0, stream>>>(
                hp, h0b, batch, nullptr, nullptr, nullptr, nullptr, nullptr, nullptr,
                es, ed, cnt, colPad, gat_b, h2b, sxO, sqO);
        } else {
            const float* sxP = stats + (size_t)(l - 1) * 4096;
            const float* sqP = sxP + 2048;
            gemm_mfma<128, true, true, false, true><<<gemm_grid, 256, 0, stream>>>(
                nullptr, h2b, batch, sxP, sqP, cntf,
                gn_w + (l - 1) * 128, gn_b + (l - 1) * 128, gn_s + (l - 1) * 128,
                Wl, nullptr, attS + l * 128, attD + l * 128, es, ed, hp, Nn);
            gat_attn<true><<<Nn / 16, 1024, 0, stream>>>(
                hp, h2b, batch, sxP, sqP, cntf,
                gn_w + (l - 1) * 128, gn_b + (l - 1) * 128, gn_s + (l - 1) * 128,
                es, ed, cnt, colPad, gat_b + l * 128, h2b, sxO, sqO);
        }
    }
    gn_apply<<<(Nn * 32 + 255) / 256, 256, 0, stream>>>(
        h2b, batch, stats + 3 * 4096, stats + 3 * 4096 + 2048, cntf,
        gn_w + 3 * 128, gn_b + 3 * 128, gn_s + 3 * 128, (float*)d_out);
    (void)in_sizes; (void)n_in; (void)out_size; (void)ws_size;
}

// Round 9
// 557.937 us; speedup vs baseline: 1.4060x; 1.4060x over previous
//
#include <hip/hip_runtime.h>
#include <cstdint>
#include <cstddef>

#define Nn   50000
#define Ee   800000
#define ETOT 850000   // edges + self loops
#define HID  128
#define Gg   16
#define RSZ  6250     // Nn/8 : dst-range size per XCD team
#define DMAX 64       // padded adjacency slots per node (max degree ~45 here)
#define NEG_SLOPE 0.2f
#define EPS_GN 1e-5f

typedef __attribute__((ext_vector_type(8))) short short8;
typedef __attribute__((ext_vector_type(4))) float f32x4;

static __device__ __forceinline__ float lrelu(float v) { return v > 0.f ? v : NEG_SLOPE * v; }

// round-to-nearest-even fp32 -> bf16 (low 16 bits of uint)
static __device__ __forceinline__ unsigned int f2bf(float x) {
    unsigned int u = __float_as_uint(x);
    return (u + 0x7fffu + ((u >> 16) & 1u)) >> 16;
}
static __device__ __forceinline__ float bf_lo(unsigned int u) { return __uint_as_float(u << 16); }
static __device__ __forceinline__ float bf_hi(unsigned int u) { return __uint_as_float(u & 0xffff0000u); }

// GraphNorm affine from raw sums: out = x*A + B reproduces
// (x - s*m)/sqrt(var+eps)*w + b with var = E[x^2] - (2s - s^2) m^2.
static __device__ __forceinline__ void gn_ab(float sx, float sq, float cn,
                                             float wv, float bv, float sv,
                                             float& A, float& B) {
    float m    = sx / cn;
    float msq  = sq / cn;
    float varo = msq - (2.f * sv - sv * sv) * m * m;
    float inv  = rsqrtf(varo + EPS_GN);
    A = inv * wv;
    B = bv - sv * m * A;
}

// ---------------------------------------------------------------------------
// Weight prep: bf16 transpose of in_W and Wg ([n][k] layout) + per-graph node
// counts (batch sorted -> run flush, 8 nodes per thread).
// ---------------------------------------------------------------------------
__global__ void prep_w(const float* __restrict__ in_W, const float* __restrict__ Wg,
                       const int* __restrict__ batch,
                       short* __restrict__ Wt0, short* __restrict__ Wtl,
                       float* __restrict__ cntf) {
    int i = blockIdx.x * 256 + threadIdx.x;
    if (i < 8192) {                       // in-proj: n = i>>6, k = i&63
        int n = i >> 6, k = i & 63;
        Wt0[i] = (short)f2bf(in_W[k * 128 + n]);
    } else if (i < 73728) {
        int j = i - 8192;                 // j = l*16384 + n*128 + k
        int l = j >> 14;
        int rkn = j & 16383;
        int n = rkn >> 7, k = rkn & 127;
        Wtl[j] = (short)f2bf(Wg[l * 16384 + k * 128 + n]);
    } else if (i < 73728 + 6250) {
        int base = (i - 73728) * 8;
        int g = batch[base];
        float c = 1.f;
        for (int k = 1; k < 8; k++) {
            int gk = batch[base + k];
            if (gk != g) { atomicAdd(&cntf[g], c); g = gk; c = 1.f; }
            else c += 1.f;
        }
        atomicAdd(&cntf[g], c);
    }
}

// ---------------------------------------------------------------------------
// Padded adjacency build, single pass, XCD-partitioned (block b&7 = dst range).
// ---------------------------------------------------------------------------
__global__ void scatter_pad(const int* __restrict__ esrc, const int* __restrict__ edst,
                            int* __restrict__ cnt, int* __restrict__ colPad) {
    int r  = blockIdx.x & 7;
    int cb = blockIdx.x >> 3;
    int nb = gridDim.x >> 3;
    int lo = r * RSZ, hi = lo + RSZ;
    for (int i = cb * 256 + threadIdx.x; i < ETOT; i += nb * 256) {
        int dst = (i < Ee) ? edst[i] : (i - Ee);
        if (dst >= lo && dst < hi) {
            int src = (i < Ee) ? esrc[i] : dst;
            int pos = atomicAdd(&cnt[dst], 1);
            if (pos < DMAX) colPad[dst * DMAX + pos] = src;
        }
    }
}

// ---------------------------------------------------------------------------
// MFMA bf16 GEMM: C[M,128] = affine?(A)[M,K] @ W[K,128] (+bias), bf16x2 out.
// Block 128x128, 4 waves (2x2 of 64x64), 16x16x32 bf16 MFMA.
// AFFINE: GraphNorm affine computed in-block from raw sums (<=2 graphs per
// 128-row tile since graphs are ~3125 nodes) into an LDS table.
// SCORES: fused es/ed (attention logits) during the C repack read-out.
// ---------------------------------------------------------------------------
template <int K, bool ABF16, bool AFFINE, bool BIAS, bool SCORES>
__global__ __launch_bounds__(256) void gemm_mfma(const float* __restrict__ Agf,
                                                 const unsigned int* __restrict__ Agb,
                                                 const int* __restrict__ batch,
                                                 const float* __restrict__ sxP,
                                                 const float* __restrict__ sqP,
                                                 const float* __restrict__ cntf,
                                                 const float* __restrict__ gw,
                                                 const float* __restrict__ gb,
                                                 const float* __restrict__ gs,
                                                 const short* __restrict__ Wt,
                                                 const float* __restrict__ bias,
                                                 const float* __restrict__ asrc,
                                                 const float* __restrict__ adst,
                                                 float* __restrict__ es,
                                                 float* __restrict__ ed,
                                                 unsigned int* __restrict__ Cb,
                                                 int M) {
    constexpr int KP = K + 8;                    // padded shorts per A row
    constexpr int ABYTES = 128 * KP * 2;
    constexpr int CBYTES = 64 * 130 * 4;
    constexpr int SBYTES = ABYTES > CBYTES ? ABYTES : CBYTES;
    __shared__ __align__(16) char smem[SBYTES];
    __shared__ float AffA[2][132], AffB[2][132];
    short* As = (short*)smem;
    float* Cs = (float*)smem;   // overlays As (used only after all MFMA reads)

    int t    = threadIdx.x;
    int lane = t & 63;
    int w    = t >> 6;
    int wm   = (w & 1) * 64;
    int wn   = (w >> 1) * 64;
    int row0 = blockIdx.x * 128;

    int g0 = 0, g1 = 0;
    if (AFFINE) {
        g0 = batch[row0];
        int lastr = row0 + 127 < M - 1 ? row0 + 127 : M - 1;
        g1 = batch[lastr];
        int sel = t >> 7;            // 0 or 1
        int c   = t & 127;
        int g   = sel ? g1 : g0;
        float A, B;
        gn_ab(sxP[g * 128 + c], sqP[g * 128 + c], cntf[g], gw[c], gb[c], gs[c], A, B);
        AffA[sel][c] = A;
        AffB[sel][c] = B;
        __syncthreads();
    }

    // ---- stage A -> bf16 LDS ----
    if (!ABF16) {
        constexpr int F4R = K / 4;               // float4 per row
        constexpr int ITERS = 128 * F4R / 256;
#pragma unroll
        for (int i = 0; i < ITERS; i++) {
            int f4 = t + 256 * i;
            int r  = f4 / F4R;
            int c4 = f4 % F4R;
            float4 v = make_float4(0.f, 0.f, 0.f, 0.f);
            int gr = row0 + r;
            if (gr < M) v = *(const float4*)(Agf + (size_t)gr * K + c4 * 4);
            uint2 pk;
            pk.x = f2bf(v.x) | (f2bf(v.y) << 16);
            pk.y = f2bf(v.z) | (f2bf(v.w) << 16);
            *(uint2*)(As + r * KP + c4 * 4) = pk;
        }
    } else {
        constexpr int U2R = K / 4;               // uint2 per row
        constexpr int ITERS = 128 * U2R / 256;
#pragma unroll
        for (int i = 0; i < ITERS; i++) {
            int u2 = t + 256 * i;
            int r  = u2 / U2R;
            int c2 = u2 % U2R;                   // uint2 index: channels c2*4..+3
            uint2 v = make_uint2(0u, 0u);
            int gr = row0 + r;
            if (gr < M) {
                v = *(const uint2*)(Agb + (size_t)gr * (K / 2) + c2 * 2);
                if (AFFINE) {
                    int sel = (batch[gr] == g0) ? 0 : 1;
                    float4 Av = *(const float4*)(&AffA[sel][c2 * 4]);
                    float4 Bv = *(const float4*)(&AffB[sel][c2 * 4]);
                    float x0 = bf_lo(v.x) * Av.x + Bv.x;
                    float x1 = bf_hi(v.x) * Av.y + Bv.y;
                    float x2 = bf_lo(v.y) * Av.z + Bv.z;
                    float x3 = bf_hi(v.y) * Av.w + Bv.w;
                    v.x = f2bf(x0) | (f2bf(x1) << 16);
                    v.y = f2bf(x2) | (f2bf(x3) << 16);
                }
            }
            *(uint2*)(As + r * KP + c2 * 4) = v;
        }
    }
    __syncthreads();

    // ---- MFMA main loop ----
    f32x4 acc[4][4] = {};
    int am = wm + (lane & 15);
    int aq = (lane >> 4) * 8;
    const short* wb = Wt + (size_t)(wn + (lane & 15)) * K + aq;
#pragma unroll
    for (int kk = 0; kk < K / 32; kk++) {
        short8 a[4], b[4];
#pragma unroll
        for (int nt = 0; nt < 4; nt++)
            b[nt] = *(const short8*)(wb + nt * 16 * K + kk * 32);
#pragma unroll
        for (int mt = 0; mt < 4; mt++)
            a[mt] = *(const short8*)(As + (am + mt * 16) * KP + kk * 32 + aq);
#pragma unroll
        for (int mt = 0; mt < 4; mt++)
#pragma unroll
            for (int nt = 0; nt < 4; nt++)
                acc[mt][nt] = __builtin_amdgcn_mfma_f32_16x16x32_bf16(
                    a[mt], b[nt], acc[mt][nt], 0, 0, 0);
    }

    // ---- epilogue: LDS repack -> packed bf16x2 (+bias, + fused scores) ----
    // C/D layout: col = lane&15 (within 16-tile), row = (lane>>4)*4 + reg
    float bv[4] = {0.f, 0.f, 0.f, 0.f};
    if (BIAS) {
#pragma unroll
        for (int nt = 0; nt < 4; nt++) bv[nt] = bias[wn + nt * 16 + (lane & 15)];
    }
    float avv[8], dvv[8];
    if (SCORES) {
        int q = t & 15;
#pragma unroll
        for (int k = 0; k < 8; k++) {
            avv[k] = asrc[q * 8 + k];
            dvv[k] = adst[q * 8 + k];
        }
    }
#pragma unroll
    for (int half = 0; half < 2; half++) {
        __syncthreads();   // As reads done / previous pack done
        if ((w & 1) == half) {
#pragma unroll
            for (int mt = 0; mt < 4; mt++)
#pragma unroll
                for (int reg = 0; reg < 4; reg++) {
                    int lr = mt * 16 + (lane >> 4) * 4 + reg;   // 0..63
#pragma unroll
                    for (int nt = 0; nt < 4; nt++)
                        Cs[lr * 130 + wn + nt * 16 + (lane & 15)] =
                            acc[mt][nt][reg] + bv[nt];
                }
        }
        __syncthreads();
#pragma unroll
        for (int i = 0; i < 4; i++) {
            int u4 = t + 256 * i;       // 0..1023
            int r  = u4 >> 4;           // 0..63
            int cu = (u4 & 15) * 4;     // uint col
            int grow = row0 + half * 64 + r;
            if (grow < M) {
                const float* cp = Cs + r * 130 + cu * 2;
                float2 p0 = *(const float2*)(cp + 0);
                float2 p1 = *(const float2*)(cp + 2);
                float2 p2 = *(const float2*)(cp + 4);
                float2 p3 = *(const float2*)(cp + 6);
                uint4 o;
                o.x = f2bf(p0.x) | (f2bf(p0.y) << 16);
                o.y = f2bf(p1.x) | (f2bf(p1.y) << 16);
                o.z = f2bf(p2.x) | (f2bf(p2.y) << 16);
                o.w = f2bf(p3.x) | (f2bf(p3.y) << 16);
                *(uint4*)(Cb + (size_t)grow * 64 + cu) = o;
                if (SCORES) {
                    float s1 = p0.x * avv[0] + p0.y * avv[1] + p1.x * avv[2] +
                               p1.y * avv[3] + p2.x * avv[4] + p2.y * avv[5] +
                               p3.x * avv[6] + p3.y * avv[7];
                    float s2 = p0.x * dvv[0] + p0.y * dvv[1] + p1.x * dvv[2] +
                               p1.y * dvv[3] + p2.x * dvv[4] + p2.y * dvv[5] +
                               p3.x * dvv[6] + p3.y * dvv[7];
                    s1 += __shfl_xor(s1, 1);
                    s2 += __shfl_xor(s2, 1);
                    if ((t & 1) == 0) {
                        int hh = (t & 15) >> 1;
                        es[(size_t)grow * 8 + hh] = s1;
                        ed[(size_t)grow * 8 + hh] = s2;
                    }
                }
            }
        }
    }
}

// ---------------------------------------------------------------------------
// GAT aggregation (proven 256-thread form): one wave per destination node.
// Weight phase: lane (slot=lane>>3, head=lane&7) computes exp weight for a
// group of 8 edge-slots. Accumulate: lane (half=lane>>5, sl=lane&31) holds
// channels 4*sl..+3 (uint2 bf16x4 gather), 2 edges per inner step. Residual
// affine computed inline from prev-layer raw sums. bf16 out. No stats here.
// ---------------------------------------------------------------------------
template <bool AFF>
__global__ __launch_bounds__(256) void gat_attn(const unsigned int* __restrict__ hp,
                                                const unsigned int* hinb,
                                                const int* __restrict__ batch,
                                                const float* __restrict__ sxP,
                                                const float* __restrict__ sqP,
                                                const float* __restrict__ cntf,
                                                const float* __restrict__ gw,
                                                const float* __restrict__ gb,
                                                const float* __restrict__ gs,
                                                const float* __restrict__ es,
                                                const float* __restrict__ ed,
                                                const int* __restrict__ cnt,
                                                const int* __restrict__ colPad,
                                                const float* __restrict__ gbias,
                                                unsigned int* outb) {
    int w    = threadIdx.x >> 6;
    int lane = threadIdx.x & 63;
    int n    = blockIdx.x * 4 + w;
    int deg  = cnt[n];
    deg = deg < DMAX ? deg : DMAX;
    const int* cbp = colPad + n * DMAX;

    int slot = lane >> 3;   // edge slot (weight phase)
    int ah   = lane & 7;    // head (weight phase)
    int half = lane >> 5;   // edge parity (accumulate phase)
    int sl   = lane & 31;   // channel group: channels 4*sl .. 4*sl+3
    int hd   = sl >> 2;     // head of this lane's channels

    float edh = ed[(size_t)n * 8 + ah];
    const unsigned int* hpl = hp + sl * 2;

    float a0 = 0.f, a1 = 0.f, a2 = 0.f, a3 = 0.f;
    float dacc = 0.f;

    int e0 = 0;
    for (; e0 + 8 <= deg; e0 += 8) {
        int src_l = cbp[e0 + slot];
        float wgt = __expf(lrelu(es[(size_t)src_l * 8 + ah] + edh));
        dacc += wgt;
#pragma unroll
        for (int jj = 0; jj < 4; jj++) {
            int e = jj * 2 + half;
            int   sj = __shfl(src_l, e * 8);
            float wj = __shfl(wgt,   e * 8 + hd);
            uint2 hv = *(const uint2*)(hpl + (size_t)sj * 64);
            a0 += wj * bf_lo(hv.x);
            a1 += wj * bf_hi(hv.x);
            a2 += wj * bf_lo(hv.y);
            a3 += wj * bf_hi(hv.y);
        }
    }
    if (e0 < deg) {
        int rem = deg - e0;                       // 1..7, wave-uniform
        int ee  = e0 + slot;
        int ec  = (slot < rem) ? ee : (deg - 1);  // rows non-empty (self-loop)
        int src_l = cbp[ec];
        float wgt = (slot < rem) ? __expf(lrelu(es[(size_t)src_l * 8 + ah] + edh)) : 0.f;
        dacc += wgt;
        int steps = (rem + 1) >> 1;
        for (int jj = 0; jj < steps; jj++) {      // weights beyond rem are 0
            int e = jj * 2 + half;
            int   sj = __shfl(src_l, e * 8);
            float wj = __shfl(wgt,   e * 8 + hd);
            uint2 hv = *(const uint2*)(hpl + (size_t)sj * 64);
            a0 += wj * bf_lo(hv.x);
            a1 += wj * bf_hi(hv.x);
            a2 += wj * bf_lo(hv.y);
            a3 += wj * bf_hi(hv.y);
        }
    }

    // combine the two halves (each saw edges of one parity)
    a0 += __shfl_xor(a0, 32);
    a1 += __shfl_xor(a1, 32);
    a2 += __shfl_xor(a2, 32);
    a3 += __shfl_xor(a3, 32);

    // denominator: sum over the 8 slots sharing head `ah`
    dacc += __shfl_xor(dacc, 8);
    dacc += __shfl_xor(dacc, 16);
    dacc += __shfl_xor(dacc, 32);
    float inv  = 1.0f / (dacc + 1e-16f);
    float winv = __shfl(inv, hd);       // lane hd has ah == hd

    if (half == 0) {
        size_t uo = (size_t)n * 64 + sl * 2;
        uint2 xv = *(const uint2*)(hinb + uo);
        float r0 = bf_lo(xv.x), r1 = bf_hi(xv.x), r2 = bf_lo(xv.y), r3 = bf_hi(xv.y);
        if (AFF) {
            int g = batch[n];
            float cn = cntf[g];
            int c = sl * 4;
            float A, B;
            gn_ab(sxP[g * 128 + c],     sqP[g * 128 + c],     cn, gw[c],     gb[c],     gs[c],     A, B);
            r0 = r0 * A + B;
            gn_ab(sxP[g * 128 + c + 1], sqP[g * 128 + c + 1], cn, gw[c + 1], gb[c + 1], gs[c + 1], A, B);
            r1 = r1 * A + B;
            gn_ab(sxP[g * 128 + c + 2], sqP[g * 128 + c + 2], cn, gw[c + 2], gb[c + 2], gs[c + 2], A, B);
            r2 = r2 * A + B;
            gn_ab(sxP[g * 128 + c + 3], sqP[g * 128 + c + 3], cn, gw[c + 3], gb[c + 3], gs[c + 3], A, B);
            r3 = r3 * A + B;
        }
        float4 bv = *(const float4*)(gbias + sl * 4);
        float o0 = a0 * winv + bv.x + r0;
        float o1 = a1 * winv + bv.y + r1;
        float o2 = a2 * winv + bv.z + r2;
        float o3 = a3 * winv + bv.w + r3;
        uint2 o;
        o.x = f2bf(o0) | (f2bf(o1) << 16);
        o.y = f2bf(o2) | (f2bf(o3) << 16);
        *(uint2*)(outb + uo) = o;
    }
}

// ---------------------------------------------------------------------------
// GraphNorm stats (bf16 input): per (g,c) raw sum/sumsq; batch sorted ->
// run flush. Consumers compute the affine inline (no gn_final pass).
// ---------------------------------------------------------------------------
#define SCHUNK 64
__global__ __launch_bounds__(128) void gn_stats(const unsigned int* __restrict__ xb,
                                                const int* __restrict__ batch,
                                                float* __restrict__ sumx,
                                                float* __restrict__ sumxx) {
    int c  = threadIdx.x;
    int cu = c >> 1;
    int hi = c & 1;
    int n0 = blockIdx.x * SCHUNK;
    int n1 = n0 + SCHUNK;
    if (n1 > Nn) n1 = Nn;
    if (n0 >= Nn) return;
    int curG = batch[n0];
    float sx = 0.f, sxx = 0.f;
    for (int n = n0; n < n1; n++) {
        int g = batch[n];
        if (g != curG) {
            atomicAdd(&sumx[curG * 128 + c], sx);
            atomicAdd(&sumxx[curG * 128 + c], sxx);
            sx = 0.f; sxx = 0.f; curG = g;
        }
        unsigned int u = xb[(size_t)n * 64 + cu];
        float v = hi ? bf_hi(u) : bf_lo(u);
        sx += v; sxx += v * v;
    }
    atomicAdd(&sumx[curG * 128 + c], sx);
    atomicAdd(&sumxx[curG * 128 + c], sxx);
}

// ---------------------------------------------------------------------------
// Final normalize -> d_out (fp32), affine computed inline from layer-3 sums.
// ---------------------------------------------------------------------------
__global__ __launch_bounds__(256) void gn_apply(const unsigned int* __restrict__ xb,
                                                const int* __restrict__ batch,
                                                const float* __restrict__ sx,
                                                const float* __restrict__ sq,
                                                const float* __restrict__ cntf,
                                                const float* __restrict__ gw,
                                                const float* __restrict__ gb,
                                                const float* __restrict__ gs,
                                                float* __restrict__ out) {
    int idx = blockIdx.x * 256 + threadIdx.x;
    int n = idx >> 5;
    if (n >= Nn) return;
    int c4 = (idx & 31) << 2;
    int g = batch[n];
    float cn = cntf[g];
    uint2 xv = *(const uint2*)(xb + (size_t)n * 64 + (c4 >> 1));
    float vv[4] = {bf_lo(xv.x), bf_hi(xv.x), bf_lo(xv.y), bf_hi(xv.y)};
    float4 o;
    float* op = (float*)&o;
#pragma unroll
    for (int k = 0; k < 4; k++) {
        int c = c4 + k;
        float A, B;
        gn_ab(sx[g * 128 + c], sq[g * 128 + c], cn, gw[c], gb[c], gs[c], A, B);
        op[k] = vv[k] * A + B;
    }
    *(float4*)(out + (size_t)n * 128 + c4) = o;
}

// ---------------------------------------------------------------------------
// Launch
// ---------------------------------------------------------------------------
extern "C" void kernel_launch(void* const* d_in, const int* in_sizes, int n_in,
                              void* d_out, int out_size, void* d_ws, size_t ws_size,
                              hipStream_t stream) {
    const float* x      = (const float*)d_in[0];
    const int*   eidx   = (const int*)d_in[1];
    const int*   batch  = (const int*)d_in[2];
    const float* in_W   = (const float*)d_in[3];
    const float* in_b   = (const float*)d_in[4];
    const float* Wg     = (const float*)d_in[5];
    const float* attS   = (const float*)d_in[6];
    const float* attD   = (const float*)d_in[7];
    const float* gat_b  = (const float*)d_in[8];
    const float* gn_w   = (const float*)d_in[9];
    const float* gn_b   = (const float*)d_in[10];
    const float* gn_s   = (const float*)d_in[11];

    const int* esrc = eidx;
    const int* edst = eidx + Ee;

    char* p = (char*)d_ws;
    auto carve = [&](size_t bytes) {
        void* r = (void*)p;
        p += (bytes + 255) & ~(size_t)255;
        return r;
    };
    unsigned int* h0b = (unsigned int*)carve((size_t)Nn * 64 * 4);  // bf16x2 hidden
    unsigned int* hp  = (unsigned int*)carve((size_t)Nn * 64 * 4);  // bf16x2 h'
    unsigned int* h2b = (unsigned int*)carve((size_t)Nn * 64 * 4);  // bf16x2 state
    float* es   = (float*)carve((size_t)Nn * 8 * 4);
    float* ed   = (float*)carve((size_t)Nn * 8 * 4);
    // single zeroed region: adjacency counts | per-graph node counts | 4x stats
    const size_t ZN = (size_t)Nn + 16 + 4 * 4096;
    int*   cnt  = (int*)carve(ZN * 4);
    float* cntf = (float*)(cnt + Nn);
    float* stats = cntf + 16;   // layer l: sumx = stats + l*4096, sumxx = +2048
    int* colPad = (int*)carve((size_t)Nn * DMAX * 4);
    short* Wt0  = (short*)carve((size_t)128 * 64 * 2);
    short* Wtl  = (short*)carve((size_t)4 * 128 * 128 * 2);

    // ---- zero + prep + adjacency build ----
    hipMemsetAsync(cnt, 0, ZN * 4, stream);
    prep_w<<<313, 256, 0, stream>>>(in_W, Wg, batch, Wt0, Wtl, cntf);
    scatter_pad<<<3072, 256, 0, stream>>>(esrc, edst, cnt, colPad);

    const int gemm_grid = (Nn + 127) / 128;  // 391

    // ---- input projection: x fp32 -> h0b bf16 (+bias) ----
    gemm_mfma<64, false, false, true, false><<<gemm_grid, 256, 0, stream>>>(
        x, nullptr, nullptr, nullptr, nullptr, nullptr, nullptr, nullptr, nullptr,
        Wt0, in_b, nullptr, nullptr, nullptr, nullptr, h0b, Nn);

    // ---- layers ----
    for (int l = 0; l < 4; l++) {
        const short* Wl = Wtl + (size_t)l * 128 * 128;
        float* sxO = stats + (size_t)l * 4096;
        float* sqO = sxO + 2048;
        if (l == 0) {
            gemm_mfma<128, true, false, false, true><<<gemm_grid, 256, 0, stream>>>(
                nullptr, h0b, nullptr, nullptr, nullptr, nullptr, nullptr, nullptr, nullptr,
                Wl, nullptr, attS, attD, es, ed, hp, Nn);
            gat_attn<false><<<Nn / 4, 256, 0, stream>>>(
                hp, h0b, batch, nullptr, nullptr, nullptr, nullptr, nullptr, nullptr,
                es, ed, cnt, colPad, gat_b, h2b);
        } else {
            const float* sxP = stats + (size_t)(l - 1) * 4096;
            const float* sqP = sxP + 2048;
            gemm_mfma<128, true, true, false, true><<<gemm_grid, 256, 0, stream>>>(
                nullptr, h2b, batch, sxP, sqP, cntf,
                gn_w + (l - 1) * 128, gn_b + (l - 1) * 128, gn_s + (l - 1) * 128,
                Wl, nullptr, attS + l * 128, attD + l * 128, es, ed, hp, Nn);
            gat_attn<true><<<Nn / 4, 256, 0, stream>>>(
                hp, h2b, batch, sxP, sqP, cntf,
                gn_w + (l - 1) * 128, gn_b + (l - 1) * 128, gn_s + (l - 1) * 128,
                es, ed, cnt, colPad, gat_b + l * 128, h2b);
        }
        gn_stats<<<(Nn + SCHUNK - 1) / SCHUNK, 128, 0, stream>>>(h2b, batch, sxO, sqO);
    }
    gn_apply<<<(Nn * 32 + 255) / 256, 256, 0, stream>>>(
        h2b, batch, stats + 3 * 4096, stats + 3 * 4096 + 2048, cntf,
        gn_w + 3 * 128, gn_b + 3 * 128, gn_s + 3 * 128, (float*)d_out);
    (void)in_sizes; (void)n_in; (void)out_size; (void)ws_size;
}